// Round 5
// baseline (221.780 us; speedup 1.0000x reference)
//
#include <hip/hip_runtime.h>
#include <hip/hip_bf16.h>

// GPT-2 attention block. Inputs/outputs fp32; internal bf16 MFMA, fp32 accum.
// B=4, S=1024, D=1024, H=16, hd=64.
//
// R17:
//  - attn_mfma REWRITTEN: no K/V LDS staging at all (K/V are L2-resident per
//    XCD thanks to bh-major mapping; m169 regime). B-fragments for QK^T and
//    PV load directly from Kp/VT as bf16x8. No barriers (P-scratch is
//    per-wave). Un-paired: 1024 blocks (bh low bits -> XCD, longest qt
//    first), 16 KB LDS, launch_bounds(256,4) -> 16 waves/CU.
//  - gemm_qkv8: Q/K epilogue now goes through LDS (dead after K-loop) with
//    col-XOR swizzle -> coalesced 16B global stores (was 128 scalar 2B).
//  - prep / gemm_out / qkv schedule verbatim from R16.

typedef __bf16 bf16x8 __attribute__((ext_vector_type(8)));
typedef __bf16 bf16x4 __attribute__((ext_vector_type(4)));
typedef float f32x4 __attribute__((ext_vector_type(4)));

__device__ __forceinline__ void load_lds16(const void* g, void* l) {
  __builtin_amdgcn_global_load_lds(
      (const __attribute__((address_space(1))) void*)g,
      (__attribute__((address_space(3))) void*)l, 16, 0, 0);
}

#define BAR8 asm volatile("s_barrier" ::: "memory")
#define LGKM0 asm volatile("s_waitcnt lgkmcnt(0)" ::: "memory")

// ---------------- fused prep: transpose w_attn, w_proj; convert x ----------------
__global__ __launch_bounds__(256) void prep(
    const float* __restrict__ x, const float* __restrict__ w_attn,
    const float* __restrict__ w_proj, __bf16* __restrict__ Xb,
    __bf16* __restrict__ WT_attn, __bf16* __restrict__ WT_proj) {
  __shared__ __bf16 tile[32][33];
  const int blk = blockIdx.x;
  const int tid = threadIdx.x;
  if (blk < 4096) {  // transpose (block-uniform branch)
    const float* W;
    __bf16* WT;
    int n0, k0, N;
    if (blk < 3072) {
      W = w_attn; WT = WT_attn; N = 3072;
      n0 = (blk % 96) * 32; k0 = (blk / 96) * 32;
    } else {
      W = w_proj; WT = WT_proj; N = 1024;
      const int t = blk - 3072;
      n0 = (t & 31) * 32; k0 = (t >> 5) * 32;
    }
    const int tx = tid & 31, ty = tid >> 5;
#pragma unroll
    for (int j = 0; j < 32; j += 8)
      tile[ty + j][tx] = (__bf16)W[(size_t)(k0 + ty + j) * N + n0 + tx];
    __syncthreads();
#pragma unroll
    for (int j = 0; j < 32; j += 8)
      WT[(size_t)(n0 + ty + j) * 1024 + k0 + tx] = tile[tx][ty + j];
  } else {  // x -> bf16, 16 elems/thread
    const size_t i = (size_t)(blk - 4096) * 4096 + tid * 16;
    const float4* xp = (const float4*)(x + i);
    float4 a = xp[0], b = xp[1], c = xp[2], d = xp[3];
    bf16x8 o0, o1;
    o0[0] = (__bf16)a.x; o0[1] = (__bf16)a.y; o0[2] = (__bf16)a.z; o0[3] = (__bf16)a.w;
    o0[4] = (__bf16)b.x; o0[5] = (__bf16)b.y; o0[6] = (__bf16)b.z; o0[7] = (__bf16)b.w;
    o1[0] = (__bf16)c.x; o1[1] = (__bf16)c.y; o1[2] = (__bf16)c.z; o1[3] = (__bf16)c.w;
    o1[4] = (__bf16)d.x; o1[5] = (__bf16)d.y; o1[6] = (__bf16)d.z; o1[7] = (__bf16)d.w;
    *(bf16x8*)(Xb + i) = o0;
    *(bf16x8*)(Xb + i + 8) = o1;
  }
}

// ================= GEMM1: 256x256 8-phase template (QKV) =================
// 512 threads = 8 waves (2M x 4N). BK=64, double-buffered 128 KB LDS.
// Schedule identical to R14-R16 (see comments there). Epilogue: all three
// segments route through LDS (dead after K-loop) for coalesced stores.

#define STG(GMAT, GROW0, K0, LOFF)                                             \
  _Pragma("unroll") for (int i_ = 0; i_ < 2; ++i_)                             \
    load_lds16((GMAT) + (size_t)((GROW0) + i_ * 64 + wave * 8 + srow) * 1024 + \
                   (K0) + schunk * 8,                                          \
               smem8 + (LOFF) + (i_ * 64 + wave * 8) * 64);

#define LDA8(BASE, MH)                                                         \
  _Pragma("unroll") for (int m_ = 0; m_ < 4; ++m_)                             \
  _Pragma("unroll") for (int kk_ = 0; kk_ < 2; ++kk_)                          \
    af[m_][kk_] = *(const bf16x8*)((BASE) + ((MH)*64 + m_ * 16 + l16) * 64 +   \
                                   (((kk_ * 4 + quad) ^ rsw) * 8));

#define LDB8(BASE, NLO)                                                        \
  _Pragma("unroll") for (int n_ = 0; n_ < 2; ++n_)                             \
  _Pragma("unroll") for (int kk_ = 0; kk_ < 2; ++kk_)                          \
    bf[(NLO) + n_][kk_] =                                                      \
        *(const bf16x8*)((BASE) + ((waveN & 1) * 64 + ((NLO) + n_) * 16 +      \
                                   l16) * 64 +                                 \
                         (((kk_ * 4 + quad) ^ rsw) * 8));

#define MFMA_HALF(MH, NLO)                                                     \
  __builtin_amdgcn_s_setprio(1);                                               \
  _Pragma("unroll") for (int m_ = 0; m_ < 4; ++m_)                             \
  _Pragma("unroll") for (int n_ = 0; n_ < 2; ++n_) {                           \
    acc[(MH)*4 + m_][(NLO) + n_] = __builtin_amdgcn_mfma_f32_16x16x32_bf16(    \
        af[m_][0], bf[(NLO) + n_][0], acc[(MH)*4 + m_][(NLO) + n_], 0, 0, 0);  \
    acc[(MH)*4 + m_][(NLO) + n_] = __builtin_amdgcn_mfma_f32_16x16x32_bf16(    \
        af[m_][1], bf[(NLO) + n_][1], acc[(MH)*4 + m_][(NLO) + n_], 0, 0, 0);  \
  }                                                                            \
  __builtin_amdgcn_s_setprio(0);

__global__ __launch_bounds__(512, 2) void gemm_qkv8(
    const __bf16* __restrict__ A, const __bf16* __restrict__ BT,
    const float* __restrict__ bias, __bf16* __restrict__ Qp,
    __bf16* __restrict__ Kp, __bf16* __restrict__ Vt) {
  __shared__ __bf16 smem8[65536];  // 128 KB
  const int tid = threadIdx.x;
  const int lane = tid & 63;
  const int wave = tid >> 6;
  const int waveM = wave >> 2;  // 0..1
  const int waveN = wave & 3;   // 0..3
  const int l16 = lane & 15;
  const int quad = lane >> 4;
  const int rsw = l16 & 7;
  const int srow = lane >> 3;            // staging row-in-8
  const int schunk = (lane & 7) ^ srow;  // pre-swizzled source chunk

  // XCD-aware 2D chunking: XCD c gets a 4(tm) x 6(tn) block of the 16x12 grid
  const int bid = blockIdx.x;
  const int c = bid & 7, l = bid >> 3;
  const int tm = (c >> 1) * 4 + l / 6;
  const int tn = (c & 1) * 6 + l % 6;
  const int rowBase = tm * 256;
  const int colBase = tn * 256;

  const __bf16* aRd = smem8 + waveM * 8192;                 // buf0 A (own half)
  const __bf16* bRd = smem8 + 16384 + (waveN >> 1) * 8192;  // buf0 B (own half)

  f32x4 acc[8][4] = {};
  bf16x8 af[4][2], bf[4][2];

  // ---- prologue: stage T0 fully, T1 {B0,B1,A0}
  STG(A, rowBase, 0, 0);
  STG(A, rowBase + 128, 0, 8192);
  STG(BT, colBase, 0, 16384);
  STG(BT, colBase + 128, 0, 24576);
  STG(BT, colBase, 64, 32768 + 16384);
  STG(BT, colBase + 128, 64, 32768 + 24576);
  STG(A, rowBase, 64, 32768);
  asm volatile("s_waitcnt vmcnt(6)" ::: "memory");  // T0 landed
  BAR8;

  for (int t = 0; t < 8; ++t) {
    const int kO = t * 128 + 64;   // odd tile K offset (for O.A1 stage)
    const int kS2 = t * 128 + 128; // prefetch tile for buf0
    const int kS3 = t * 128 + 192; // prefetch tile for buf1
    const bool s2 = kS2 < 1024;
    const bool s3 = kS3 < 1024;

    // ---- phase 1: read E.A-mh0 + E.B-n01 ; stage O.A1
    LDA8(aRd, 0);
    LDB8(bRd, 0);
    STG(A, rowBase + 128, kO, 32768 + 8192);
    BAR8; LGKM0;
    MFMA_HALF(0, 0);
    BAR8;

    // ---- phase 2: read E.B-n23
    LDB8(bRd, 2);
    BAR8; LGKM0;
    MFMA_HALF(0, 2);
    BAR8;

    // ---- phase 3: read E.A-mh1 ; stage (E+2).B0
    LDA8(aRd, 1);
    if (s2) { STG(BT, colBase, kS2, 16384); }
    BAR8; LGKM0;
    MFMA_HALF(1, 2);
    BAR8;

    // ---- phase 4: stage (E+2).B1 + (E+2).A0 ; counted vmcnt
    if (s2) {
      STG(BT, colBase + 128, kS2, 24576);
      STG(A, rowBase, kS2, 0);
      asm volatile("s_waitcnt vmcnt(6)" ::: "memory");  // all of O landed
    } else {
      asm volatile("s_waitcnt vmcnt(0)" ::: "memory");  // last iter: drain
    }
    BAR8;
    MFMA_HALF(1, 0);
    BAR8;

    // ---- phase 5: read O.A-mh0 + O.B-n01 ; stage (E+2).A1
    LDA8(aRd + 32768, 0);
    LDB8(bRd + 32768, 0);
    if (s2) { STG(A, rowBase + 128, kS2, 8192); }
    BAR8; LGKM0;
    MFMA_HALF(0, 0);
    BAR8;

    // ---- phase 6: read O.B-n23
    LDB8(bRd + 32768, 2);
    BAR8; LGKM0;
    MFMA_HALF(0, 2);
    BAR8;

    // ---- phase 7: read O.A-mh1 ; stage (O+2).B0
    LDA8(aRd + 32768, 1);
    if (s3) { STG(BT, colBase, kS3, 32768 + 16384); }
    BAR8; LGKM0;
    MFMA_HALF(1, 2);
    BAR8;

    // ---- phase 8: stage (O+2).B1 + (O+2).A0 ; counted vmcnt
    if (s3) {
      STG(BT, colBase + 128, kS3, 32768 + 24576);
      STG(A, rowBase, kS3, 32768);
    }
    asm volatile("s_waitcnt vmcnt(6)" ::: "memory");  // all of E+2 landed
    BAR8;
    MFMA_HALF(1, 0);
    BAR8;
  }

  const int seg = colBase >> 10;  // 0=Q 1=K 2=V (block-uniform)
  if (seg == 2) {
    // ---- V epilogue: transpose 256x256 tile in LDS, write VT[bh][d][s].
#pragma unroll
    for (int mm = 0; mm < 8; ++mm) {
      const int r0 = waveM * 128 + mm * 16 + quad * 4;
#pragma unroll
      for (int n = 0; n < 4; ++n) {
        const int cR = waveN * 64 + n * 16 + l16;
        const float bv = bias[colBase + cR];
        bf16x4 pk;
#pragma unroll
        for (int r = 0; r < 4; ++r) pk[r] = (__bf16)(acc[mm][n][r] + bv);
        *(bf16x4*)(&smem8[cR * 256 + (r0 ^ (l16 << 4))]) = pk;
      }
    }
    __syncthreads();
    const int b_ = rowBase >> 10;
    const int s0 = rowBase & 1023;
    const int hBase = (colBase & 1023) >> 6;
    const int ch = lane & 31;
#pragma unroll
    for (int p = 0; p < 16; ++p) {
      const int c2 = p * 16 + wave * 2 + (lane >> 5);
      bf16x8 v =
          *(const bf16x8*)(&smem8[c2 * 256 + ((ch * 8) ^ ((c2 & 15) << 4))]);
      const int bhd = (b_ * 16 + hBase + (c2 >> 6)) * 64 + (c2 & 63);
      *(bf16x8*)(&Vt[(size_t)bhd * 1024 + s0 + ch * 8]) = v;
    }
  } else {
    // ---- Q/K epilogue through LDS: row-major with col-XOR, then coalesced
    // 16B stores. LDS elem addr = rowL*256 + (colL ^ (((rowL>>2)&3)<<4));
    // XOR bits 4-5 are disjoint from in-chunk bits 0-2 -> 8-elem chunks stay
    // contiguous and the map is bijective.
    __bf16* dst = (seg == 0) ? Qp : Kp;
#pragma unroll
    for (int mm = 0; mm < 8; ++mm) {
#pragma unroll
      for (int n = 0; n < 4; ++n) {
        const int colL = waveN * 64 + n * 16 + l16;
        const float bv = bias[colBase + colL];
#pragma unroll
        for (int r = 0; r < 4; ++r) {
          const int rowL = waveM * 128 + mm * 16 + quad * 4 + r;
          smem8[rowL * 256 + (colL ^ (((rowL >> 2) & 3) << 4))] =
              (__bf16)(acc[mm][n][r] + bv);
        }
      }
    }
    __syncthreads();
#pragma unroll
    for (int p = 0; p < 16; ++p) {
      const int chunk = p * 512 + tid;
      const int rowL = chunk >> 5;
      const int colL0 = (chunk & 31) * 8;
      bf16x8 v = *(const bf16x8*)(
          &smem8[rowL * 256 + (colL0 ^ (((rowL >> 2) & 3) << 4))]);
      const int row = rowBase + rowL;
      const int cc = (colBase + colL0) & 1023;
      const int bh = ((row >> 10) << 4) + (cc >> 6);
      *(bf16x8*)(&dst[((size_t)bh << 16) + (size_t)(row & 1023) * 64 +
                      (cc & 63)]) = v;
    }
  }
}

// ---------------- GEMM2: out = A @ WT^T + bias, depth-2 pipelined ----------------
__global__ __launch_bounds__(256) void gemm_out(
    const __bf16* __restrict__ A, const __bf16* __restrict__ BT,
    const float* __restrict__ bias, float* __restrict__ C) {
  __shared__ __bf16 sA[3][128 * 32];  // 24 KB
  __shared__ __bf16 sB[3][128 * 32];  // 24 KB
  const int tid = threadIdx.x;
  const int lane = tid & 63;
  const int wave = tid >> 6;
  const int waveM = wave >> 1, waveN = wave & 1;
  const int quad = lane >> 4;
  const int l16 = lane & 15;
  const int rowBase = blockIdx.x * 128;
  const int colBase = blockIdx.y * 128;
  const int rIn = lane >> 2;
  const int sIn = lane & 3;
  const int gc = sIn ^ (rIn & 3) ^ ((rIn >> 2) & 3);
  const int readSlot = quad ^ (l16 & 3) ^ ((l16 >> 2) & 3);
  f32x4 acc[4][4] = {};

#define GO_STAGE(bi, k0_)                                                      \
  _Pragma("unroll") for (int j_ = 0; j_ < 2; ++j_) {                           \
    const int rb = wave * 32 + j_ * 16;                                        \
    load_lds16(&A[(size_t)(rowBase + rb + rIn) * 1024 + (k0_) + gc * 8],       \
               &sA[bi][rb * 32]);                                              \
    load_lds16(&BT[(size_t)(colBase + rb + rIn) * 1024 + (k0_) + gc * 8],      \
               &sB[bi][rb * 32]);                                              \
  }

  GO_STAGE(0, 0);
  GO_STAGE(1, 32);
  asm volatile("s_waitcnt vmcnt(4)" ::: "memory");  // tile 0 landed
  BAR8;

#pragma unroll
  for (int i = 0; i < 32; ++i) {
    if (i + 2 < 32) { GO_STAGE((i + 2) % 3, (i + 2) * 32); }
    const __bf16* sAc = sA[i % 3];
    const __bf16* sBc = sB[i % 3];
    bf16x8 af[4], bfr[4];
#pragma unroll
    for (int mt = 0; mt < 4; ++mt)
      af[mt] = *(const bf16x8*)(&sAc[(waveM * 64 + mt * 16 + l16) * 32 +
                                     readSlot * 8]);
#pragma unroll
    for (int nt = 0; nt < 4; ++nt)
      bfr[nt] = *(const bf16x8*)(&sBc[(waveN * 64 + nt * 16 + l16) * 32 +
                                      readSlot * 8]);
    __builtin_amdgcn_s_setprio(1);
#pragma unroll
    for (int mt = 0; mt < 4; ++mt)
#pragma unroll
      for (int nt = 0; nt < 4; ++nt)
        acc[mt][nt] = __builtin_amdgcn_mfma_f32_16x16x32_bf16(
            af[mt], bfr[nt], acc[mt][nt], 0, 0, 0);
    __builtin_amdgcn_s_setprio(0);
    if (i + 1 < 32) {
      if (i + 2 < 32) {
        asm volatile("s_waitcnt vmcnt(4)" ::: "memory");  // tile i+1 landed
      } else {
        asm volatile("s_waitcnt vmcnt(0)" ::: "memory");  // drain last stage
      }
      BAR8;
    }
  }

#pragma unroll
  for (int mt = 0; mt < 4; ++mt) {
    const int row = rowBase + waveM * 64 + mt * 16 + quad * 4;
#pragma unroll
    for (int nt = 0; nt < 4; ++nt) {
      const int col = colBase + waveN * 64 + nt * 16 + l16;
      const float bv = bias[col];
#pragma unroll
      for (int r = 0; r < 4; ++r)
        C[(size_t)(row + r) * 1024 + col] = acc[mt][nt][r] + bv;
    }
  }
}

// ---------------- flash attention (R17: barrier-free, direct-from-L2) ----------
// 1024 blocks = 16 qt x 64 bh (bh in low bits -> XCD = bh%8; qt reversed so
// longest blocks dispatch first). 4 waves/block, wave owns 16 q-rows.
// K and V^T fragments load straight from global (L2-resident per XCD).
// Only LDS: per-wave P scratch (16 KB). No __syncthreads anywhere.
__global__ __launch_bounds__(256, 4) void attn_mfma(
    const __bf16* __restrict__ Qp, const __bf16* __restrict__ Kp,
    const __bf16* __restrict__ VT, __bf16* __restrict__ Aout) {
  __shared__ __bf16 sP[4 * 16 * 128];  // 16 KB, per-wave P regions

  const int tid = threadIdx.x;
  const int lane = tid & 63;
  const int wave = tid >> 6;
  const int quad = lane >> 4;
  const int l16 = lane & 15;
  const int swq = l16 & 7;

  const int bh = blockIdx.x & 63;
  const int qt = 15 - (blockIdx.x >> 6);  // longest first
  const int b = bh >> 4, h = bh & 15;
  const int qb = qt * 64;
  const int ktmax = qt >> 1;

  const __bf16* Qb = Qp + ((size_t)bh << 16);
  const __bf16* Kb = Kp + ((size_t)bh << 16);
  const __bf16* VTb = VT + (size_t)bh * 64 * 1024;

  bf16x8 qA0, qA1;
  {
    const __bf16* qr = Qb + (size_t)(qb + wave * 16 + l16) * 64 + quad * 8;
    qA0 = *(const bf16x8*)qr;
    qA1 = *(const bf16x8*)(qr + 32);
  }

  f32x4 O[4] = {};
  float ps[4] = {0.f, 0.f, 0.f, 0.f};
  __bf16* pw = sP + wave * 2048;

  for (int kt = 0; kt <= ktmax; ++kt) {
    const int kb = kt * 128;
    float sc[8][4];

    // ---- QK^T: B-fragment direct from Kp (B[k=quad*8+j][col=key=l16])
    __builtin_amdgcn_s_setprio(1);
#pragma unroll
    for (int n = 0; n < 8; ++n) {
      const __bf16* kr = Kb + (size_t)(kb + n * 16 + l16) * 64 + quad * 8;
      bf16x8 kB0 = *(const bf16x8*)kr;
      bf16x8 kB1 = *(const bf16x8*)(kr + 32);
      f32x4 cacc = {};
      cacc = __builtin_amdgcn_mfma_f32_16x16x32_bf16(qA0, kB0, cacc, 0, 0, 0);
      cacc = __builtin_amdgcn_mfma_f32_16x16x32_bf16(qA1, kB1, cacc, 0, 0, 0);
#pragma unroll
      for (int r = 0; r < 4; ++r) sc[n][r] = cacc[r] * 0.125f;
    }
    __builtin_amdgcn_s_setprio(0);

    // ---- causal mask on the diagonal tile
    if (kt == ktmax) {
#pragma unroll
      for (int n = 0; n < 8; ++n) {
        const int kg = kb + n * 16 + l16;
#pragma unroll
        for (int r = 0; r < 4; ++r)
          if (kg > qb + wave * 16 + quad * 4 + r) sc[n][r] = -1.0e30f;
      }
    }

    // ---- softmax numerator + row-sum
#pragma unroll
    for (int n = 0; n < 8; ++n)
#pragma unroll
      for (int r = 0; r < 4; ++r) {
        float p = __expf(fminf(sc[n][r], 60.0f));
        sc[n][r] = p;
        ps[r] += p;
      }

    // ---- P -> per-wave LDS (swizzled), then PV with V^T direct from global
    {
      const int kb8 = l16 >> 3, lo = l16 & 7;
#pragma unroll
      for (int n = 0; n < 8; ++n) {
        const int chunk = n * 2 + kb8;
#pragma unroll
        for (int r = 0; r < 4; ++r) {
          const int q = quad * 4 + r;
          pw[q * 128 + ((chunk ^ (q & 7)) << 3) + lo] = (__bf16)sc[n][r];
        }
      }
    }
    __builtin_amdgcn_s_setprio(1);
#pragma unroll
    for (int cc = 0; cc < 4; ++cc) {
      bf16x8 pA = *(const bf16x8*)(&pw[l16 * 128 + (((cc * 4 + quad) ^ swq) << 3)]);
#pragma unroll
      for (int nt = 0; nt < 4; ++nt) {
        bf16x8 vB = *(const bf16x8*)(VTb + (size_t)(nt * 16 + l16) * 1024 +
                                     kb + (cc * 4 + quad) * 8);
        O[nt] = __builtin_amdgcn_mfma_f32_16x16x32_bf16(pA, vB, O[nt], 0, 0, 0);
      }
    }
    __builtin_amdgcn_s_setprio(0);
  }

  // ---- epilogue
  float inv[4];
#pragma unroll
  for (int r = 0; r < 4; ++r) {
    float pa = ps[r];
    pa += __shfl_xor(pa, 1);
    pa += __shfl_xor(pa, 2);
    pa += __shfl_xor(pa, 4);
    pa += __shfl_xor(pa, 8);
    inv[r] = 1.0f / pa;
  }
#pragma unroll
  for (int nt = 0; nt < 4; ++nt) {
#pragma unroll
    for (int r = 0; r < 4; ++r) {
      const int q = qb + wave * 16 + quad * 4 + r;
      Aout[((size_t)b * 1024 + q) * 1024 + h * 64 + nt * 16 + l16] =
          (__bf16)(O[nt][r] * inv[r]);
    }
  }
}

// ---------------- launch ----------------
extern "C" void kernel_launch(void* const* d_in, const int* in_sizes, int n_in,
                              void* d_out, int out_size, void* d_ws,
                              size_t ws_size, hipStream_t stream) {
  const float* x      = (const float*)d_in[0];
  const float* w_attn = (const float*)d_in[1];
  const float* b_attn = (const float*)d_in[2];
  const float* w_proj = (const float*)d_in[3];
  const float* b_proj = (const float*)d_in[4];
  float* out = (float*)d_out;

  char* ws = (char*)d_ws;
  __bf16* WT_attn = (__bf16*)(ws);                  //  6 MB
  __bf16* WT_proj = (__bf16*)(ws + 6291456);        //  2 MB
  __bf16* Xb      = (__bf16*)(ws + 8388608);        //  8 MB
  __bf16* Qp      = (__bf16*)(ws + 16777216);       //  8 MB [bh][s][64]
  __bf16* Kp      = (__bf16*)(ws + 25165824);       //  8 MB [bh][s][64]
  __bf16* VT      = (__bf16*)(ws + 33554432);       //  8 MB [bh][d][s]
  __bf16* Aattn   = (__bf16*)(ws + 41943040);       //  8 MB (end 50 MB)

  prep<<<5120, 256, 0, stream>>>(x, w_attn, w_proj, Xb, WT_attn, WT_proj);
  gemm_qkv8<<<192, 512, 0, stream>>>(Xb, WT_attn, b_attn, Qp, Kp, VT);
  attn_mfma<<<1024, 256, 0, stream>>>(Qp, Kp, VT, Aattn);
  gemm_out<<<dim3(32, 8), 256, 0, stream>>>(Aattn, WT_proj, b_proj, out);
}

// Round 6
// 169.935 us; speedup vs baseline: 1.3051x; 1.3051x over previous
//
#include <hip/hip_runtime.h>
#include <hip/hip_bf16.h>

// GPT-2 attention block. Inputs/outputs fp32; internal bf16 MFMA, fp32 accum.
// B=4, S=1024, D=1024, H=16, hd=64.
//
// R18:
//  - attn_mfma: back to STAGED K/V (R17's direct-global was -33us: per-wave
//    load duplication + MFMA chained on L2 latency). New structure: unpaired
//    1024 blocks (bh low bits -> XCD; longest qt first), single-buffered
//    sK/sV + HALVED per-wave P scratch = 40 KB LDS -> 4 blocks/CU (16
//    waves/CU, was 8). P processed in two 64-k halves interleaved with PV.
//  - gemm_qkv8: epilogues reverted to R16 (measured 50.2 us; R17's LDS-routed
//    Q/K epilogue was an unattributed regression suspect).
//  - prep / gemm_out verbatim from R16.

typedef __bf16 bf16x8 __attribute__((ext_vector_type(8)));
typedef __bf16 bf16x4 __attribute__((ext_vector_type(4)));
typedef float f32x4 __attribute__((ext_vector_type(4)));

__device__ __forceinline__ void load_lds16(const void* g, void* l) {
  __builtin_amdgcn_global_load_lds(
      (const __attribute__((address_space(1))) void*)g,
      (__attribute__((address_space(3))) void*)l, 16, 0, 0);
}

#define BAR8 asm volatile("s_barrier" ::: "memory")
#define LGKM0 asm volatile("s_waitcnt lgkmcnt(0)" ::: "memory")

// ---------------- fused prep: transpose w_attn, w_proj; convert x ----------------
__global__ __launch_bounds__(256) void prep(
    const float* __restrict__ x, const float* __restrict__ w_attn,
    const float* __restrict__ w_proj, __bf16* __restrict__ Xb,
    __bf16* __restrict__ WT_attn, __bf16* __restrict__ WT_proj) {
  __shared__ __bf16 tile[32][33];
  const int blk = blockIdx.x;
  const int tid = threadIdx.x;
  if (blk < 4096) {  // transpose (block-uniform branch)
    const float* W;
    __bf16* WT;
    int n0, k0, N;
    if (blk < 3072) {
      W = w_attn; WT = WT_attn; N = 3072;
      n0 = (blk % 96) * 32; k0 = (blk / 96) * 32;
    } else {
      W = w_proj; WT = WT_proj; N = 1024;
      const int t = blk - 3072;
      n0 = (t & 31) * 32; k0 = (t >> 5) * 32;
    }
    const int tx = tid & 31, ty = tid >> 5;
#pragma unroll
    for (int j = 0; j < 32; j += 8)
      tile[ty + j][tx] = (__bf16)W[(size_t)(k0 + ty + j) * N + n0 + tx];
    __syncthreads();
#pragma unroll
    for (int j = 0; j < 32; j += 8)
      WT[(size_t)(n0 + ty + j) * 1024 + k0 + tx] = tile[tx][ty + j];
  } else {  // x -> bf16, 16 elems/thread
    const size_t i = (size_t)(blk - 4096) * 4096 + tid * 16;
    const float4* xp = (const float4*)(x + i);
    float4 a = xp[0], b = xp[1], c = xp[2], d = xp[3];
    bf16x8 o0, o1;
    o0[0] = (__bf16)a.x; o0[1] = (__bf16)a.y; o0[2] = (__bf16)a.z; o0[3] = (__bf16)a.w;
    o0[4] = (__bf16)b.x; o0[5] = (__bf16)b.y; o0[6] = (__bf16)b.z; o0[7] = (__bf16)b.w;
    o1[0] = (__bf16)c.x; o1[1] = (__bf16)c.y; o1[2] = (__bf16)c.z; o1[3] = (__bf16)c.w;
    o1[4] = (__bf16)d.x; o1[5] = (__bf16)d.y; o1[6] = (__bf16)d.z; o1[7] = (__bf16)d.w;
    *(bf16x8*)(Xb + i) = o0;
    *(bf16x8*)(Xb + i + 8) = o1;
  }
}

// ================= GEMM1: 256x256 8-phase template (QKV) =================
// 512 threads = 8 waves (2M x 4N). BK=64, double-buffered 128 KB LDS.
// Schedule identical to R14-R16. Epilogues = R16 (V via LDS transpose,
// Q/K direct packed stores).

#define STG(GMAT, GROW0, K0, LOFF)                                             \
  _Pragma("unroll") for (int i_ = 0; i_ < 2; ++i_)                             \
    load_lds16((GMAT) + (size_t)((GROW0) + i_ * 64 + wave * 8 + srow) * 1024 + \
                   (K0) + schunk * 8,                                          \
               smem8 + (LOFF) + (i_ * 64 + wave * 8) * 64);

#define LDA8(BASE, MH)                                                         \
  _Pragma("unroll") for (int m_ = 0; m_ < 4; ++m_)                             \
  _Pragma("unroll") for (int kk_ = 0; kk_ < 2; ++kk_)                          \
    af[m_][kk_] = *(const bf16x8*)((BASE) + ((MH)*64 + m_ * 16 + l16) * 64 +   \
                                   (((kk_ * 4 + quad) ^ rsw) * 8));

#define LDB8(BASE, NLO)                                                        \
  _Pragma("unroll") for (int n_ = 0; n_ < 2; ++n_)                             \
  _Pragma("unroll") for (int kk_ = 0; kk_ < 2; ++kk_)                          \
    bf[(NLO) + n_][kk_] =                                                      \
        *(const bf16x8*)((BASE) + ((waveN & 1) * 64 + ((NLO) + n_) * 16 +      \
                                   l16) * 64 +                                 \
                         (((kk_ * 4 + quad) ^ rsw) * 8));

#define MFMA_HALF(MH, NLO)                                                     \
  __builtin_amdgcn_s_setprio(1);                                               \
  _Pragma("unroll") for (int m_ = 0; m_ < 4; ++m_)                             \
  _Pragma("unroll") for (int n_ = 0; n_ < 2; ++n_) {                           \
    acc[(MH)*4 + m_][(NLO) + n_] = __builtin_amdgcn_mfma_f32_16x16x32_bf16(    \
        af[m_][0], bf[(NLO) + n_][0], acc[(MH)*4 + m_][(NLO) + n_], 0, 0, 0);  \
    acc[(MH)*4 + m_][(NLO) + n_] = __builtin_amdgcn_mfma_f32_16x16x32_bf16(    \
        af[m_][1], bf[(NLO) + n_][1], acc[(MH)*4 + m_][(NLO) + n_], 0, 0, 0);  \
  }                                                                            \
  __builtin_amdgcn_s_setprio(0);

__global__ __launch_bounds__(512, 2) void gemm_qkv8(
    const __bf16* __restrict__ A, const __bf16* __restrict__ BT,
    const float* __restrict__ bias, __bf16* __restrict__ Qp,
    __bf16* __restrict__ Kp, __bf16* __restrict__ Vt) {
  __shared__ __bf16 smem8[65536];  // 128 KB
  const int tid = threadIdx.x;
  const int lane = tid & 63;
  const int wave = tid >> 6;
  const int waveM = wave >> 2;  // 0..1
  const int waveN = wave & 3;   // 0..3
  const int l16 = lane & 15;
  const int quad = lane >> 4;
  const int rsw = l16 & 7;
  const int srow = lane >> 3;            // staging row-in-8
  const int schunk = (lane & 7) ^ srow;  // pre-swizzled source chunk

  // XCD-aware 2D chunking: XCD c gets a 4(tm) x 6(tn) block of the 16x12 grid
  const int bid = blockIdx.x;
  const int c = bid & 7, l = bid >> 3;
  const int tm = (c >> 1) * 4 + l / 6;
  const int tn = (c & 1) * 6 + l % 6;
  const int rowBase = tm * 256;
  const int colBase = tn * 256;

  const __bf16* aRd = smem8 + waveM * 8192;                 // buf0 A (own half)
  const __bf16* bRd = smem8 + 16384 + (waveN >> 1) * 8192;  // buf0 B (own half)

  f32x4 acc[8][4] = {};
  bf16x8 af[4][2], bf[4][2];

  // ---- prologue: stage T0 fully, T1 {B0,B1,A0}
  STG(A, rowBase, 0, 0);
  STG(A, rowBase + 128, 0, 8192);
  STG(BT, colBase, 0, 16384);
  STG(BT, colBase + 128, 0, 24576);
  STG(BT, colBase, 64, 32768 + 16384);
  STG(BT, colBase + 128, 64, 32768 + 24576);
  STG(A, rowBase, 64, 32768);
  asm volatile("s_waitcnt vmcnt(6)" ::: "memory");  // T0 landed
  BAR8;

  for (int t = 0; t < 8; ++t) {
    const int kO = t * 128 + 64;   // odd tile K offset (for O.A1 stage)
    const int kS2 = t * 128 + 128; // prefetch tile for buf0
    const int kS3 = t * 128 + 192; // prefetch tile for buf1
    const bool s2 = kS2 < 1024;
    const bool s3 = kS3 < 1024;

    // ---- phase 1: read E.A-mh0 + E.B-n01 ; stage O.A1
    LDA8(aRd, 0);
    LDB8(bRd, 0);
    STG(A, rowBase + 128, kO, 32768 + 8192);
    BAR8; LGKM0;
    MFMA_HALF(0, 0);
    BAR8;

    // ---- phase 2: read E.B-n23
    LDB8(bRd, 2);
    BAR8; LGKM0;
    MFMA_HALF(0, 2);
    BAR8;

    // ---- phase 3: read E.A-mh1 ; stage (E+2).B0
    LDA8(aRd, 1);
    if (s2) { STG(BT, colBase, kS2, 16384); }
    BAR8; LGKM0;
    MFMA_HALF(1, 2);
    BAR8;

    // ---- phase 4: stage (E+2).B1 + (E+2).A0 ; counted vmcnt
    if (s2) {
      STG(BT, colBase + 128, kS2, 24576);
      STG(A, rowBase, kS2, 0);
      asm volatile("s_waitcnt vmcnt(6)" ::: "memory");  // all of O landed
    } else {
      asm volatile("s_waitcnt vmcnt(0)" ::: "memory");  // last iter: drain
    }
    BAR8;
    MFMA_HALF(1, 0);
    BAR8;

    // ---- phase 5: read O.A-mh0 + O.B-n01 ; stage (E+2).A1
    LDA8(aRd + 32768, 0);
    LDB8(bRd + 32768, 0);
    if (s2) { STG(A, rowBase + 128, kS2, 8192); }
    BAR8; LGKM0;
    MFMA_HALF(0, 0);
    BAR8;

    // ---- phase 6: read O.B-n23
    LDB8(bRd + 32768, 2);
    BAR8; LGKM0;
    MFMA_HALF(0, 2);
    BAR8;

    // ---- phase 7: read O.A-mh1 ; stage (O+2).B0
    LDA8(aRd + 32768, 1);
    if (s3) { STG(BT, colBase, kS3, 32768 + 16384); }
    BAR8; LGKM0;
    MFMA_HALF(1, 2);
    BAR8;

    // ---- phase 8: stage (O+2).B1 + (O+2).A0 ; counted vmcnt
    if (s3) {
      STG(BT, colBase + 128, kS3, 32768 + 24576);
      STG(A, rowBase, kS3, 32768);
    }
    asm volatile("s_waitcnt vmcnt(6)" ::: "memory");  // all of E+2 landed
    BAR8;
    MFMA_HALF(1, 0);
    BAR8;
  }

  const int seg = colBase >> 10;  // 0=Q 1=K 2=V (block-uniform)
  if (seg == 2) {
    // ---- V epilogue: transpose 256x256 tile in LDS, write VT[bh][d][s].
#pragma unroll
    for (int mm = 0; mm < 8; ++mm) {
      const int r0 = waveM * 128 + mm * 16 + quad * 4;
#pragma unroll
      for (int n = 0; n < 4; ++n) {
        const int cR = waveN * 64 + n * 16 + l16;
        const float bv = bias[colBase + cR];
        bf16x4 pk;
#pragma unroll
        for (int r = 0; r < 4; ++r) pk[r] = (__bf16)(acc[mm][n][r] + bv);
        *(bf16x4*)(&smem8[cR * 256 + (r0 ^ (l16 << 4))]) = pk;
      }
    }
    __syncthreads();
    const int b_ = rowBase >> 10;
    const int s0 = rowBase & 1023;
    const int hBase = (colBase & 1023) >> 6;
    const int ch = lane & 31;
#pragma unroll
    for (int p = 0; p < 16; ++p) {
      const int c2 = p * 16 + wave * 2 + (lane >> 5);
      bf16x8 v =
          *(const bf16x8*)(&smem8[c2 * 256 + ((ch * 8) ^ ((c2 & 15) << 4))]);
      const int bhd = (b_ * 16 + hBase + (c2 >> 6)) * 64 + (c2 & 63);
      *(bf16x8*)(&Vt[(size_t)bhd * 1024 + s0 + ch * 8]) = v;
    }
  } else {
    // ---- Q/K epilogue: packed [bh][s][64] (R16 version)
#pragma unroll
    for (int mm = 0; mm < 8; ++mm) {
      const int row0 = rowBase + waveM * 128 + mm * 16 + quad * 4;
#pragma unroll
      for (int n = 0; n < 4; ++n) {
        const int col = colBase + waveN * 64 + n * 16 + l16;
        const float bv = bias[col];
        const int cc = col & 1023;
        __bf16* dst = (seg == 0) ? Qp : Kp;
#pragma unroll
        for (int r = 0; r < 4; ++r) {
          const int row = row0 + r;
          const float v = acc[mm][n][r] + bv;
          const int bh = ((row >> 10) << 4) + (cc >> 6);
          dst[((size_t)bh << 16) + (size_t)(row & 1023) * 64 + (cc & 63)] =
              (__bf16)v;
        }
      }
    }
  }
}

// ---------------- GEMM2: out = A @ WT^T + bias, depth-2 pipelined ----------------
__global__ __launch_bounds__(256) void gemm_out(
    const __bf16* __restrict__ A, const __bf16* __restrict__ BT,
    const float* __restrict__ bias, float* __restrict__ C) {
  __shared__ __bf16 sA[3][128 * 32];  // 24 KB
  __shared__ __bf16 sB[3][128 * 32];  // 24 KB
  const int tid = threadIdx.x;
  const int lane = tid & 63;
  const int wave = tid >> 6;
  const int waveM = wave >> 1, waveN = wave & 1;
  const int quad = lane >> 4;
  const int l16 = lane & 15;
  const int rowBase = blockIdx.x * 128;
  const int colBase = blockIdx.y * 128;
  const int rIn = lane >> 2;
  const int sIn = lane & 3;
  const int gc = sIn ^ (rIn & 3) ^ ((rIn >> 2) & 3);
  const int readSlot = quad ^ (l16 & 3) ^ ((l16 >> 2) & 3);
  f32x4 acc[4][4] = {};

#define GO_STAGE(bi, k0_)                                                      \
  _Pragma("unroll") for (int j_ = 0; j_ < 2; ++j_) {                           \
    const int rb = wave * 32 + j_ * 16;                                        \
    load_lds16(&A[(size_t)(rowBase + rb + rIn) * 1024 + (k0_) + gc * 8],       \
               &sA[bi][rb * 32]);                                              \
    load_lds16(&BT[(size_t)(colBase + rb + rIn) * 1024 + (k0_) + gc * 8],      \
               &sB[bi][rb * 32]);                                              \
  }

  GO_STAGE(0, 0);
  GO_STAGE(1, 32);
  asm volatile("s_waitcnt vmcnt(4)" ::: "memory");  // tile 0 landed
  BAR8;

#pragma unroll
  for (int i = 0; i < 32; ++i) {
    if (i + 2 < 32) { GO_STAGE((i + 2) % 3, (i + 2) * 32); }
    const __bf16* sAc = sA[i % 3];
    const __bf16* sBc = sB[i % 3];
    bf16x8 af[4], bfr[4];
#pragma unroll
    for (int mt = 0; mt < 4; ++mt)
      af[mt] = *(const bf16x8*)(&sAc[(waveM * 64 + mt * 16 + l16) * 32 +
                                     readSlot * 8]);
#pragma unroll
    for (int nt = 0; nt < 4; ++nt)
      bfr[nt] = *(const bf16x8*)(&sBc[(waveN * 64 + nt * 16 + l16) * 32 +
                                      readSlot * 8]);
    __builtin_amdgcn_s_setprio(1);
#pragma unroll
    for (int mt = 0; mt < 4; ++mt)
#pragma unroll
      for (int nt = 0; nt < 4; ++nt)
        acc[mt][nt] = __builtin_amdgcn_mfma_f32_16x16x32_bf16(
            af[mt], bfr[nt], acc[mt][nt], 0, 0, 0);
    __builtin_amdgcn_s_setprio(0);
    if (i + 1 < 32) {
      if (i + 2 < 32) {
        asm volatile("s_waitcnt vmcnt(4)" ::: "memory");  // tile i+1 landed
      } else {
        asm volatile("s_waitcnt vmcnt(0)" ::: "memory");  // drain last stage
      }
      BAR8;
    }
  }

#pragma unroll
  for (int mt = 0; mt < 4; ++mt) {
    const int row = rowBase + waveM * 64 + mt * 16 + quad * 4;
#pragma unroll
    for (int nt = 0; nt < 4; ++nt) {
      const int col = colBase + waveN * 64 + nt * 16 + l16;
      const float bv = bias[col];
#pragma unroll
      for (int r = 0; r < 4; ++r)
        C[(size_t)(row + r) * 1024 + col] = acc[mt][nt][r] + bv;
    }
  }
}

// ---------------- flash attention (R18: staged, unpaired, 40KB, 4 blk/CU) ------
// 1024 blocks = 16 qt x 64 bh. bh in low bits -> XCD = bh%8 (all 16 qt-blocks
// of a bh share one XCD's L2 copy of K/V). qt reversed -> longest first.
// Single-buffered sK/sV staged via global_load_lds (shared by 4 waves);
// per-wave P scratch HALVED to [16][64] (k processed in two halves,
// interleaved with PV) -> 40 KB total -> 4 blocks/CU.
__global__ __launch_bounds__(256, 4) void attn_mfma(
    const __bf16* __restrict__ Qp, const __bf16* __restrict__ Kp,
    const __bf16* __restrict__ VT, __bf16* __restrict__ Aout) {
  __shared__ __bf16 sK[128 * 64];     // 16 KB, swizzled packed K lines
  __shared__ __bf16 sV[64 * 128];     // 16 KB, swizzled V^T
  __shared__ __bf16 sP[4 * 16 * 64];  // 8 KB, per-wave P half-regions

  const int tid = threadIdx.x;
  const int lane = tid & 63;
  const int wave = tid >> 6;
  const int quad = lane >> 4;
  const int l16 = lane & 15;
  const int swq = l16 & 7;

  const int bh = blockIdx.x & 63;
  const int qt = 15 - (blockIdx.x >> 6);  // longest first
  const int b = bh >> 4, h = bh & 15;
  const int qb = qt * 64;
  const int ktmax = qt >> 1;

  const __bf16* Qb = Qp + ((size_t)bh << 16);
  const __bf16* Kb = Kp + ((size_t)bh << 16);
  const __bf16* VTb = VT + (size_t)bh * 64 * 1024;

  bf16x8 qA0, qA1;
  {
    const __bf16* qr = Qb + (size_t)(qb + wave * 16 + l16) * 64 + quad * 8;
    qA0 = *(const bf16x8*)qr;
    qA1 = *(const bf16x8*)(qr + 32);
  }

  f32x4 O[4] = {};
  float ps[4] = {0.f, 0.f, 0.f, 0.f};
  __bf16* pw = sP + wave * 1024;

  for (int kt = 0; kt <= ktmax; ++kt) {
    const int kb = kt * 128;
    __syncthreads();  // prior iter's sK/sV reads complete

    // ---- DMA stage K: sK[key][slot s] = line chunk s^(key&7)
#pragma unroll
    for (int i = 0; i < 4; ++i) {
      const int rb = wave * 32 + i * 8;
      load_lds16(Kb + (size_t)(kb + rb + (lane >> 3)) * 64 +
                     (((lane & 7) ^ ((lane >> 3) & 7)) << 3),
                 &sK[rb * 64]);
    }
    // ---- DMA stage V^T: sV[d][slot s] = key-chunk s^(d&7)
#pragma unroll
    for (int i = 0; i < 4; ++i) {
      const int db = wave * 16 + i * 4;
      const int d = db + (lane >> 4);
      load_lds16(VTb + (size_t)d * 1024 + kb + (((lane & 15) ^ (d & 7)) << 3),
                 &sV[db * 128]);
    }
    __syncthreads();  // staged (drains vmcnt)

    // ---- QK^T
    float sc[8][4];
    __builtin_amdgcn_s_setprio(1);
#pragma unroll
    for (int n = 0; n < 8; ++n) {
      const int key = n * 16 + l16;
      bf16x8 kB0 = *(const bf16x8*)(&sK[key * 64 + ((quad ^ swq) << 3)]);
      bf16x8 kB1 = *(const bf16x8*)(&sK[key * 64 + (((quad + 4) ^ swq) << 3)]);
      f32x4 cacc = {};
      cacc = __builtin_amdgcn_mfma_f32_16x16x32_bf16(qA0, kB0, cacc, 0, 0, 0);
      cacc = __builtin_amdgcn_mfma_f32_16x16x32_bf16(qA1, kB1, cacc, 0, 0, 0);
#pragma unroll
      for (int r = 0; r < 4; ++r) sc[n][r] = cacc[r] * 0.125f;
    }
    __builtin_amdgcn_s_setprio(0);

    // ---- causal mask on the diagonal tile
    if (kt == ktmax) {
#pragma unroll
      for (int n = 0; n < 8; ++n) {
        const int kg = kb + n * 16 + l16;
#pragma unroll
        for (int r = 0; r < 4; ++r)
          if (kg > qb + wave * 16 + quad * 4 + r) sc[n][r] = -1.0e30f;
      }
    }

    // ---- softmax numerator + row-sum
#pragma unroll
    for (int n = 0; n < 8; ++n)
#pragma unroll
      for (int r = 0; r < 4; ++r) {
        float p = __expf(fminf(sc[n][r], 60.0f));
        sc[n][r] = p;
        ps[r] += p;
      }

    // ---- PV in two k-halves through the 2KB per-wave P scratch.
    // Write: P[q][64h + c*8+lo] at pw[q*64 + ((c^(q&7))<<3) + lo], c in 0..7.
    // Read (cc in {2h,2h+1}): chunk_rel = (cc-2h)*4+quad; row l16.
    const int kb8 = l16 >> 3, lo = l16 & 7;
#pragma unroll
    for (int hf = 0; hf < 2; ++hf) {
#pragma unroll
      for (int n = 4 * hf; n < 4 * hf + 4; ++n) {
        const int crel = (n - 4 * hf) * 2 + kb8;
#pragma unroll
        for (int r = 0; r < 4; ++r) {
          const int q = quad * 4 + r;
          pw[q * 64 + ((crel ^ (q & 7)) << 3) + lo] = (__bf16)sc[n][r];
        }
      }
      __builtin_amdgcn_s_setprio(1);
#pragma unroll
      for (int cc = 2 * hf; cc < 2 * hf + 2; ++cc) {
        const int crel = (cc - 2 * hf) * 4 + quad;
        bf16x8 pA = *(const bf16x8*)(&pw[l16 * 64 + ((crel ^ swq) << 3)]);
#pragma unroll
        for (int nt = 0; nt < 4; ++nt) {
          bf16x8 vB = *(const bf16x8*)(&sV[(nt * 16 + l16) * 128 +
                                           (((cc * 4 + quad) ^ swq) << 3)]);
          O[nt] = __builtin_amdgcn_mfma_f32_16x16x32_bf16(pA, vB, O[nt], 0, 0, 0);
        }
      }
      __builtin_amdgcn_s_setprio(0);
    }
  }

  // ---- epilogue
  float inv[4];
#pragma unroll
  for (int r = 0; r < 4; ++r) {
    float pa = ps[r];
    pa += __shfl_xor(pa, 1);
    pa += __shfl_xor(pa, 2);
    pa += __shfl_xor(pa, 4);
    pa += __shfl_xor(pa, 8);
    inv[r] = 1.0f / pa;
  }
#pragma unroll
  for (int nt = 0; nt < 4; ++nt) {
#pragma unroll
    for (int r = 0; r < 4; ++r) {
      const int q = qb + wave * 16 + quad * 4 + r;
      Aout[((size_t)b * 1024 + q) * 1024 + h * 64 + nt * 16 + l16] =
          (__bf16)(O[nt][r] * inv[r]);
    }
  }
}

// ---------------- launch ----------------
extern "C" void kernel_launch(void* const* d_in, const int* in_sizes, int n_in,
                              void* d_out, int out_size, void* d_ws,
                              size_t ws_size, hipStream_t stream) {
  const float* x      = (const float*)d_in[0];
  const float* w_attn = (const float*)d_in[1];
  const float* b_attn = (const float*)d_in[2];
  const float* w_proj = (const float*)d_in[3];
  const float* b_proj = (const float*)d_in[4];
  float* out = (float*)d_out;

  char* ws = (char*)d_ws;
  __bf16* WT_attn = (__bf16*)(ws);                  //  6 MB
  __bf16* WT_proj = (__bf16*)(ws + 6291456);        //  2 MB
  __bf16* Xb      = (__bf16*)(ws + 8388608);        //  8 MB
  __bf16* Qp      = (__bf16*)(ws + 16777216);       //  8 MB [bh][s][64]
  __bf16* Kp      = (__bf16*)(ws + 25165824);       //  8 MB [bh][s][64]
  __bf16* VT      = (__bf16*)(ws + 33554432);       //  8 MB [bh][d][s]
  __bf16* Aattn   = (__bf16*)(ws + 41943040);       //  8 MB (end 50 MB)

  prep<<<5120, 256, 0, stream>>>(x, w_attn, w_proj, Xb, WT_attn, WT_proj);
  gemm_qkv8<<<192, 512, 0, stream>>>(Xb, WT_attn, b_attn, Qp, Kp, VT);
  attn_mfma<<<1024, 256, 0, stream>>>(Qp, Kp, VT, Aattn);
  gemm_out<<<dim3(32, 8), 256, 0, stream>>>(Aattn, WT_proj, b_proj, out);
}

// Round 7
// 163.532 us; speedup vs baseline: 1.3562x; 1.0392x over previous
//
#include <hip/hip_runtime.h>
#include <hip/hip_bf16.h>

// GPT-2 attention block. Inputs/outputs fp32; internal bf16 MFMA, fp32 accum.
// B=4, S=1024, D=1024, H=16, hd=64.
//
// R19: attn_mfma = paired tiles (R16 structure, 52 tile-stages/bh) but with
//      8-wave (512-thread) blocks: waves 0-3 own the long q-tile, 4-7 the
//      short one. Staging shared 8-ways (per-wave loads halved), 16 waves/CU
//      (was 8). LDS 80 KB = sK dbuf 32 + sV dbuf 32 + 8x2KB halved-P (R18's
//      verified two-half scheme). Short-tile waves co-stage even when their
//      compute is done. qkv/prep/gemm_out verbatim from R18 (= R16).

typedef __bf16 bf16x8 __attribute__((ext_vector_type(8)));
typedef __bf16 bf16x4 __attribute__((ext_vector_type(4)));
typedef float f32x4 __attribute__((ext_vector_type(4)));

__device__ __forceinline__ void load_lds16(const void* g, void* l) {
  __builtin_amdgcn_global_load_lds(
      (const __attribute__((address_space(1))) void*)g,
      (__attribute__((address_space(3))) void*)l, 16, 0, 0);
}

#define BAR8 asm volatile("s_barrier" ::: "memory")
#define LGKM0 asm volatile("s_waitcnt lgkmcnt(0)" ::: "memory")

// ---------------- fused prep: transpose w_attn, w_proj; convert x ----------------
__global__ __launch_bounds__(256) void prep(
    const float* __restrict__ x, const float* __restrict__ w_attn,
    const float* __restrict__ w_proj, __bf16* __restrict__ Xb,
    __bf16* __restrict__ WT_attn, __bf16* __restrict__ WT_proj) {
  __shared__ __bf16 tile[32][33];
  const int blk = blockIdx.x;
  const int tid = threadIdx.x;
  if (blk < 4096) {  // transpose (block-uniform branch)
    const float* W;
    __bf16* WT;
    int n0, k0, N;
    if (blk < 3072) {
      W = w_attn; WT = WT_attn; N = 3072;
      n0 = (blk % 96) * 32; k0 = (blk / 96) * 32;
    } else {
      W = w_proj; WT = WT_proj; N = 1024;
      const int t = blk - 3072;
      n0 = (t & 31) * 32; k0 = (t >> 5) * 32;
    }
    const int tx = tid & 31, ty = tid >> 5;
#pragma unroll
    for (int j = 0; j < 32; j += 8)
      tile[ty + j][tx] = (__bf16)W[(size_t)(k0 + ty + j) * N + n0 + tx];
    __syncthreads();
#pragma unroll
    for (int j = 0; j < 32; j += 8)
      WT[(size_t)(n0 + ty + j) * 1024 + k0 + tx] = tile[tx][ty + j];
  } else {  // x -> bf16, 16 elems/thread
    const size_t i = (size_t)(blk - 4096) * 4096 + tid * 16;
    const float4* xp = (const float4*)(x + i);
    float4 a = xp[0], b = xp[1], c = xp[2], d = xp[3];
    bf16x8 o0, o1;
    o0[0] = (__bf16)a.x; o0[1] = (__bf16)a.y; o0[2] = (__bf16)a.z; o0[3] = (__bf16)a.w;
    o0[4] = (__bf16)b.x; o0[5] = (__bf16)b.y; o0[6] = (__bf16)b.z; o0[7] = (__bf16)b.w;
    o1[0] = (__bf16)c.x; o1[1] = (__bf16)c.y; o1[2] = (__bf16)c.z; o1[3] = (__bf16)c.w;
    o1[4] = (__bf16)d.x; o1[5] = (__bf16)d.y; o1[6] = (__bf16)d.z; o1[7] = (__bf16)d.w;
    *(bf16x8*)(Xb + i) = o0;
    *(bf16x8*)(Xb + i + 8) = o1;
  }
}

// ================= GEMM1: 256x256 8-phase template (QKV) =================
// 512 threads = 8 waves (2M x 4N). BK=64, double-buffered 128 KB LDS.
// Schedule identical to R14-R16. Epilogues = R16.

#define STG(GMAT, GROW0, K0, LOFF)                                             \
  _Pragma("unroll") for (int i_ = 0; i_ < 2; ++i_)                             \
    load_lds16((GMAT) + (size_t)((GROW0) + i_ * 64 + wave * 8 + srow) * 1024 + \
                   (K0) + schunk * 8,                                          \
               smem8 + (LOFF) + (i_ * 64 + wave * 8) * 64);

#define LDA8(BASE, MH)                                                         \
  _Pragma("unroll") for (int m_ = 0; m_ < 4; ++m_)                             \
  _Pragma("unroll") for (int kk_ = 0; kk_ < 2; ++kk_)                          \
    af[m_][kk_] = *(const bf16x8*)((BASE) + ((MH)*64 + m_ * 16 + l16) * 64 +   \
                                   (((kk_ * 4 + quad) ^ rsw) * 8));

#define LDB8(BASE, NLO)                                                        \
  _Pragma("unroll") for (int n_ = 0; n_ < 2; ++n_)                             \
  _Pragma("unroll") for (int kk_ = 0; kk_ < 2; ++kk_)                          \
    bf[(NLO) + n_][kk_] =                                                      \
        *(const bf16x8*)((BASE) + ((waveN & 1) * 64 + ((NLO) + n_) * 16 +      \
                                   l16) * 64 +                                 \
                         (((kk_ * 4 + quad) ^ rsw) * 8));

#define MFMA_HALF(MH, NLO)                                                     \
  __builtin_amdgcn_s_setprio(1);                                               \
  _Pragma("unroll") for (int m_ = 0; m_ < 4; ++m_)                             \
  _Pragma("unroll") for (int n_ = 0; n_ < 2; ++n_) {                           \
    acc[(MH)*4 + m_][(NLO) + n_] = __builtin_amdgcn_mfma_f32_16x16x32_bf16(    \
        af[m_][0], bf[(NLO) + n_][0], acc[(MH)*4 + m_][(NLO) + n_], 0, 0, 0);  \
    acc[(MH)*4 + m_][(NLO) + n_] = __builtin_amdgcn_mfma_f32_16x16x32_bf16(    \
        af[m_][1], bf[(NLO) + n_][1], acc[(MH)*4 + m_][(NLO) + n_], 0, 0, 0);  \
  }                                                                            \
  __builtin_amdgcn_s_setprio(0);

__global__ __launch_bounds__(512, 2) void gemm_qkv8(
    const __bf16* __restrict__ A, const __bf16* __restrict__ BT,
    const float* __restrict__ bias, __bf16* __restrict__ Qp,
    __bf16* __restrict__ Kp, __bf16* __restrict__ Vt) {
  __shared__ __bf16 smem8[65536];  // 128 KB
  const int tid = threadIdx.x;
  const int lane = tid & 63;
  const int wave = tid >> 6;
  const int waveM = wave >> 2;  // 0..1
  const int waveN = wave & 3;   // 0..3
  const int l16 = lane & 15;
  const int quad = lane >> 4;
  const int rsw = l16 & 7;
  const int srow = lane >> 3;            // staging row-in-8
  const int schunk = (lane & 7) ^ srow;  // pre-swizzled source chunk

  // XCD-aware 2D chunking: XCD c gets a 4(tm) x 6(tn) block of the 16x12 grid
  const int bid = blockIdx.x;
  const int c = bid & 7, l = bid >> 3;
  const int tm = (c >> 1) * 4 + l / 6;
  const int tn = (c & 1) * 6 + l % 6;
  const int rowBase = tm * 256;
  const int colBase = tn * 256;

  const __bf16* aRd = smem8 + waveM * 8192;                 // buf0 A (own half)
  const __bf16* bRd = smem8 + 16384 + (waveN >> 1) * 8192;  // buf0 B (own half)

  f32x4 acc[8][4] = {};
  bf16x8 af[4][2], bf[4][2];

  // ---- prologue: stage T0 fully, T1 {B0,B1,A0}
  STG(A, rowBase, 0, 0);
  STG(A, rowBase + 128, 0, 8192);
  STG(BT, colBase, 0, 16384);
  STG(BT, colBase + 128, 0, 24576);
  STG(BT, colBase, 64, 32768 + 16384);
  STG(BT, colBase + 128, 64, 32768 + 24576);
  STG(A, rowBase, 64, 32768);
  asm volatile("s_waitcnt vmcnt(6)" ::: "memory");  // T0 landed
  BAR8;

  for (int t = 0; t < 8; ++t) {
    const int kO = t * 128 + 64;   // odd tile K offset (for O.A1 stage)
    const int kS2 = t * 128 + 128; // prefetch tile for buf0
    const int kS3 = t * 128 + 192; // prefetch tile for buf1
    const bool s2 = kS2 < 1024;
    const bool s3 = kS3 < 1024;

    // ---- phase 1: read E.A-mh0 + E.B-n01 ; stage O.A1
    LDA8(aRd, 0);
    LDB8(bRd, 0);
    STG(A, rowBase + 128, kO, 32768 + 8192);
    BAR8; LGKM0;
    MFMA_HALF(0, 0);
    BAR8;

    // ---- phase 2: read E.B-n23
    LDB8(bRd, 2);
    BAR8; LGKM0;
    MFMA_HALF(0, 2);
    BAR8;

    // ---- phase 3: read E.A-mh1 ; stage (E+2).B0
    LDA8(aRd, 1);
    if (s2) { STG(BT, colBase, kS2, 16384); }
    BAR8; LGKM0;
    MFMA_HALF(1, 2);
    BAR8;

    // ---- phase 4: stage (E+2).B1 + (E+2).A0 ; counted vmcnt
    if (s2) {
      STG(BT, colBase + 128, kS2, 24576);
      STG(A, rowBase, kS2, 0);
      asm volatile("s_waitcnt vmcnt(6)" ::: "memory");  // all of O landed
    } else {
      asm volatile("s_waitcnt vmcnt(0)" ::: "memory");  // last iter: drain
    }
    BAR8;
    MFMA_HALF(1, 0);
    BAR8;

    // ---- phase 5: read O.A-mh0 + O.B-n01 ; stage (E+2).A1
    LDA8(aRd + 32768, 0);
    LDB8(bRd + 32768, 0);
    if (s2) { STG(A, rowBase + 128, kS2, 8192); }
    BAR8; LGKM0;
    MFMA_HALF(0, 0);
    BAR8;

    // ---- phase 6: read O.B-n23
    LDB8(bRd + 32768, 2);
    BAR8; LGKM0;
    MFMA_HALF(0, 2);
    BAR8;

    // ---- phase 7: read O.A-mh1 ; stage (O+2).B0
    LDA8(aRd + 32768, 1);
    if (s3) { STG(BT, colBase, kS3, 32768 + 16384); }
    BAR8; LGKM0;
    MFMA_HALF(1, 2);
    BAR8;

    // ---- phase 8: stage (O+2).B1 + (O+2).A0 ; counted vmcnt
    if (s3) {
      STG(BT, colBase + 128, kS3, 32768 + 24576);
      STG(A, rowBase, kS3, 32768);
    }
    asm volatile("s_waitcnt vmcnt(6)" ::: "memory");  // all of E+2 landed
    BAR8;
    MFMA_HALF(1, 0);
    BAR8;
  }

  const int seg = colBase >> 10;  // 0=Q 1=K 2=V (block-uniform)
  if (seg == 2) {
    // ---- V epilogue: transpose 256x256 tile in LDS, write VT[bh][d][s].
#pragma unroll
    for (int mm = 0; mm < 8; ++mm) {
      const int r0 = waveM * 128 + mm * 16 + quad * 4;
#pragma unroll
      for (int n = 0; n < 4; ++n) {
        const int cR = waveN * 64 + n * 16 + l16;
        const float bv = bias[colBase + cR];
        bf16x4 pk;
#pragma unroll
        for (int r = 0; r < 4; ++r) pk[r] = (__bf16)(acc[mm][n][r] + bv);
        *(bf16x4*)(&smem8[cR * 256 + (r0 ^ (l16 << 4))]) = pk;
      }
    }
    __syncthreads();
    const int b_ = rowBase >> 10;
    const int s0 = rowBase & 1023;
    const int hBase = (colBase & 1023) >> 6;
    const int ch = lane & 31;
#pragma unroll
    for (int p = 0; p < 16; ++p) {
      const int c2 = p * 16 + wave * 2 + (lane >> 5);
      bf16x8 v =
          *(const bf16x8*)(&smem8[c2 * 256 + ((ch * 8) ^ ((c2 & 15) << 4))]);
      const int bhd = (b_ * 16 + hBase + (c2 >> 6)) * 64 + (c2 & 63);
      *(bf16x8*)(&Vt[(size_t)bhd * 1024 + s0 + ch * 8]) = v;
    }
  } else {
    // ---- Q/K epilogue: packed [bh][s][64]
#pragma unroll
    for (int mm = 0; mm < 8; ++mm) {
      const int row0 = rowBase + waveM * 128 + mm * 16 + quad * 4;
#pragma unroll
      for (int n = 0; n < 4; ++n) {
        const int col = colBase + waveN * 64 + n * 16 + l16;
        const float bv = bias[col];
        const int cc = col & 1023;
        __bf16* dst = (seg == 0) ? Qp : Kp;
#pragma unroll
        for (int r = 0; r < 4; ++r) {
          const int row = row0 + r;
          const float v = acc[mm][n][r] + bv;
          const int bh = ((row >> 10) << 4) + (cc >> 6);
          dst[((size_t)bh << 16) + (size_t)(row & 1023) * 64 + (cc & 63)] =
              (__bf16)v;
        }
      }
    }
  }
}

// ---------------- GEMM2: out = A @ WT^T + bias, depth-2 pipelined ----------------
__global__ __launch_bounds__(256) void gemm_out(
    const __bf16* __restrict__ A, const __bf16* __restrict__ BT,
    const float* __restrict__ bias, float* __restrict__ C) {
  __shared__ __bf16 sA[3][128 * 32];  // 24 KB
  __shared__ __bf16 sB[3][128 * 32];  // 24 KB
  const int tid = threadIdx.x;
  const int lane = tid & 63;
  const int wave = tid >> 6;
  const int waveM = wave >> 1, waveN = wave & 1;
  const int quad = lane >> 4;
  const int l16 = lane & 15;
  const int rowBase = blockIdx.x * 128;
  const int colBase = blockIdx.y * 128;
  const int rIn = lane >> 2;
  const int sIn = lane & 3;
  const int gc = sIn ^ (rIn & 3) ^ ((rIn >> 2) & 3);
  const int readSlot = quad ^ (l16 & 3) ^ ((l16 >> 2) & 3);
  f32x4 acc[4][4] = {};

#define GO_STAGE(bi, k0_)                                                      \
  _Pragma("unroll") for (int j_ = 0; j_ < 2; ++j_) {                           \
    const int rb = wave * 32 + j_ * 16;                                        \
    load_lds16(&A[(size_t)(rowBase + rb + rIn) * 1024 + (k0_) + gc * 8],       \
               &sA[bi][rb * 32]);                                              \
    load_lds16(&BT[(size_t)(colBase + rb + rIn) * 1024 + (k0_) + gc * 8],      \
               &sB[bi][rb * 32]);                                              \
  }

  GO_STAGE(0, 0);
  GO_STAGE(1, 32);
  asm volatile("s_waitcnt vmcnt(4)" ::: "memory");  // tile 0 landed
  BAR8;

#pragma unroll
  for (int i = 0; i < 32; ++i) {
    if (i + 2 < 32) { GO_STAGE((i + 2) % 3, (i + 2) * 32); }
    const __bf16* sAc = sA[i % 3];
    const __bf16* sBc = sB[i % 3];
    bf16x8 af[4], bfr[4];
#pragma unroll
    for (int mt = 0; mt < 4; ++mt)
      af[mt] = *(const bf16x8*)(&sAc[(waveM * 64 + mt * 16 + l16) * 32 +
                                     readSlot * 8]);
#pragma unroll
    for (int nt = 0; nt < 4; ++nt)
      bfr[nt] = *(const bf16x8*)(&sBc[(waveN * 64 + nt * 16 + l16) * 32 +
                                      readSlot * 8]);
    __builtin_amdgcn_s_setprio(1);
#pragma unroll
    for (int mt = 0; mt < 4; ++mt)
#pragma unroll
      for (int nt = 0; nt < 4; ++nt)
        acc[mt][nt] = __builtin_amdgcn_mfma_f32_16x16x32_bf16(
            af[mt], bfr[nt], acc[mt][nt], 0, 0, 0);
    __builtin_amdgcn_s_setprio(0);
    if (i + 1 < 32) {
      if (i + 2 < 32) {
        asm volatile("s_waitcnt vmcnt(4)" ::: "memory");  // tile i+1 landed
      } else {
        asm volatile("s_waitcnt vmcnt(0)" ::: "memory");  // drain last stage
      }
      BAR8;
    }
  }

#pragma unroll
  for (int mt = 0; mt < 4; ++mt) {
    const int row = rowBase + waveM * 64 + mt * 16 + quad * 4;
#pragma unroll
    for (int nt = 0; nt < 4; ++nt) {
      const int col = colBase + waveN * 64 + nt * 16 + l16;
      const float bv = bias[col];
#pragma unroll
      for (int r = 0; r < 4; ++r)
        C[(size_t)(row + r) * 1024 + col] = acc[mt][nt][r] + bv;
    }
  }
}

// ---------------- flash attention (R19: paired tiles, 8-wave blocks) ----------
// 512 blocks = 8 pr x 64 bh (bh low bits -> XCD = bh%8). 512 threads:
// waves 0-3 own q-tile B (long, qbB=(15-pr)*64), waves 4-7 own q-tile A
// (short, qbA=pr*64); wave covers 16 q-rows. K/V double-buffered, staged
// cooperatively by all 8 waves (per-wave loads halved vs R16); prefetch
// issued before compute, vmcnt(0)+barrier after. Halved per-wave P scratch
// (R18 scheme). LDS 80 KB -> 2 blocks/CU = 16 waves/CU.
__global__ __launch_bounds__(512, 4) void attn_mfma(
    const __bf16* __restrict__ Qp, const __bf16* __restrict__ Kp,
    const __bf16* __restrict__ VT, __bf16* __restrict__ Aout) {
  __shared__ __bf16 sK[2][128 * 64];  // 32 KB
  __shared__ __bf16 sV[2][64 * 128];  // 32 KB
  __shared__ __bf16 sP[8 * 16 * 64];  // 16 KB, per-wave halved P

  const int tid = threadIdx.x;
  const int lane = tid & 63;
  const int wave = tid >> 6;       // 0..7
  const int wq = wave & 3;         // row-group within my tile
  const int tileSel = wave >> 2;   // 0 = long tile B, 1 = short tile A
  const int quad = lane >> 4;
  const int l16 = lane & 15;
  const int swq = l16 & 7;

  const int bh = blockIdx.x & 63;
  const int pr = blockIdx.x >> 6;  // 0..7
  const int b = bh >> 4, h = bh & 15;
  const int qbB = (15 - pr) * 64, qbA = pr * 64;
  const int ktB_max = (15 - pr) >> 1, ktA_max = pr >> 1;
  const int myQb = tileSel ? qbA : qbB;
  const int myKt = tileSel ? ktA_max : ktB_max;

  const __bf16* Qb = Qp + ((size_t)bh << 16);
  const __bf16* Kb = Kp + ((size_t)bh << 16);
  const __bf16* VTb = VT + (size_t)bh * 64 * 1024;

  bf16x8 qA0, qA1;
  {
    const __bf16* qr = Qb + (size_t)(myQb + wq * 16 + l16) * 64 + quad * 8;
    qA0 = *(const bf16x8*)qr;
    qA1 = *(const bf16x8*)(qr + 32);
  }

  f32x4 O[4] = {};
  float ps[4] = {0.f, 0.f, 0.f, 0.f};
  __bf16* pw = sP + wave * 1024;  // [16][64] per wave

  // 8-wave cooperative stage: K = 16 units (8 rows each), V = 16 units
  // (4 d-rows each); each wave does 2 K-units + 2 V-units.
#define ATTN_STAGE(bi, kbase)                                                  \
  _Pragma("unroll") for (int i_ = 0; i_ < 2; ++i_) {                           \
    const int rb = wave * 16 + i_ * 8;                                         \
    load_lds16(Kb + (size_t)((kbase) + rb + (lane >> 3)) * 64 +                \
                   (((lane & 7) ^ ((lane >> 3) & 7)) << 3),                    \
               &sK[bi][rb * 64]);                                              \
  }                                                                            \
  _Pragma("unroll") for (int i_ = 0; i_ < 2; ++i_) {                           \
    const int db = wave * 8 + i_ * 4;                                          \
    const int d = db + (lane >> 4);                                            \
    load_lds16(VTb + (size_t)d * 1024 + (kbase) +                              \
                   (((lane & 15) ^ (d & 7)) << 3),                             \
               &sV[bi][db * 128]);                                             \
  }

  // prologue: stage tile 0
  ATTN_STAGE(0, 0);
  asm volatile("s_waitcnt vmcnt(0)" ::: "memory");
  BAR8;

  for (int kt = 0; kt <= ktB_max; ++kt) {
    const int kb = kt * 128;
    const int cur = kt & 1;
    // issue next tile's loads first; they land under this iter's compute.
    if (kt < ktB_max) { ATTN_STAGE(cur ^ 1, kb + 128); }

    if (kt <= myKt) {  // wave-uniform
      const __bf16* skc = sK[cur];
      const __bf16* svc = sV[cur];

      // ---- QK^T
      float sc[8][4];
      __builtin_amdgcn_s_setprio(1);
#pragma unroll
      for (int n = 0; n < 8; ++n) {
        const int key = n * 16 + l16;
        bf16x8 kB0 = *(const bf16x8*)(&skc[key * 64 + ((quad ^ swq) << 3)]);
        bf16x8 kB1 = *(const bf16x8*)(&skc[key * 64 + (((quad + 4) ^ swq) << 3)]);
        f32x4 cacc = {};
        cacc = __builtin_amdgcn_mfma_f32_16x16x32_bf16(qA0, kB0, cacc, 0, 0, 0);
        cacc = __builtin_amdgcn_mfma_f32_16x16x32_bf16(qA1, kB1, cacc, 0, 0, 0);
#pragma unroll
        for (int r = 0; r < 4; ++r) sc[n][r] = cacc[r] * 0.125f;
      }
      __builtin_amdgcn_s_setprio(0);

      // ---- causal mask on the diagonal tile
      if (kt == myKt) {
#pragma unroll
        for (int n = 0; n < 8; ++n) {
          const int kg = kb + n * 16 + l16;
#pragma unroll
          for (int r = 0; r < 4; ++r)
            if (kg > myQb + wq * 16 + quad * 4 + r) sc[n][r] = -1.0e30f;
        }
      }

      // ---- softmax numerator + row-sum
#pragma unroll
      for (int n = 0; n < 8; ++n)
#pragma unroll
        for (int r = 0; r < 4; ++r) {
          float p = __expf(fminf(sc[n][r], 60.0f));
          sc[n][r] = p;
          ps[r] += p;
        }

      // ---- PV in two k-halves through the 2KB per-wave P scratch.
      const int kb8 = l16 >> 3, lo = l16 & 7;
#pragma unroll
      for (int hf = 0; hf < 2; ++hf) {
#pragma unroll
        for (int n = 4 * hf; n < 4 * hf + 4; ++n) {
          const int crel = (n - 4 * hf) * 2 + kb8;
#pragma unroll
          for (int r = 0; r < 4; ++r) {
            const int q = quad * 4 + r;
            pw[q * 64 + ((crel ^ (q & 7)) << 3) + lo] = (__bf16)sc[n][r];
          }
        }
        __builtin_amdgcn_s_setprio(1);
#pragma unroll
        for (int cc = 2 * hf; cc < 2 * hf + 2; ++cc) {
          const int crel = (cc - 2 * hf) * 4 + quad;
          bf16x8 pA = *(const bf16x8*)(&pw[l16 * 64 + ((crel ^ swq) << 3)]);
#pragma unroll
          for (int nt = 0; nt < 4; ++nt) {
            bf16x8 vB = *(const bf16x8*)(&svc[(nt * 16 + l16) * 128 +
                                              (((cc * 4 + quad) ^ swq) << 3)]);
            O[nt] = __builtin_amdgcn_mfma_f32_16x16x32_bf16(pA, vB, O[nt], 0, 0, 0);
          }
        }
        __builtin_amdgcn_s_setprio(0);
      }
    }

    // next buffer staged + all waves done reading the current one.
    if (kt < ktB_max) {
      asm volatile("s_waitcnt vmcnt(0)" ::: "memory");
      BAR8;
    }
  }

  // ---- epilogue
  float inv[4];
#pragma unroll
  for (int r = 0; r < 4; ++r) {
    float pa = ps[r];
    pa += __shfl_xor(pa, 1);
    pa += __shfl_xor(pa, 2);
    pa += __shfl_xor(pa, 4);
    pa += __shfl_xor(pa, 8);
    inv[r] = 1.0f / pa;
  }
#pragma unroll
  for (int nt = 0; nt < 4; ++nt) {
#pragma unroll
    for (int r = 0; r < 4; ++r) {
      const int q = myQb + wq * 16 + quad * 4 + r;
      Aout[((size_t)b * 1024 + q) * 1024 + h * 64 + nt * 16 + l16] =
          (__bf16)(O[nt][r] * inv[r]);
    }
  }
}

// ---------------- launch ----------------
extern "C" void kernel_launch(void* const* d_in, const int* in_sizes, int n_in,
                              void* d_out, int out_size, void* d_ws,
                              size_t ws_size, hipStream_t stream) {
  const float* x      = (const float*)d_in[0];
  const float* w_attn = (const float*)d_in[1];
  const float* b_attn = (const float*)d_in[2];
  const float* w_proj = (const float*)d_in[3];
  const float* b_proj = (const float*)d_in[4];
  float* out = (float*)d_out;

  char* ws = (char*)d_ws;
  __bf16* WT_attn = (__bf16*)(ws);                  //  6 MB
  __bf16* WT_proj = (__bf16*)(ws + 6291456);        //  2 MB
  __bf16* Xb      = (__bf16*)(ws + 8388608);        //  8 MB
  __bf16* Qp      = (__bf16*)(ws + 16777216);       //  8 MB [bh][s][64]
  __bf16* Kp      = (__bf16*)(ws + 25165824);       //  8 MB [bh][s][64]
  __bf16* VT      = (__bf16*)(ws + 33554432);       //  8 MB [bh][d][s]
  __bf16* Aattn   = (__bf16*)(ws + 41943040);       //  8 MB (end 50 MB)

  prep<<<5120, 256, 0, stream>>>(x, w_attn, w_proj, Xb, WT_attn, WT_proj);
  gemm_qkv8<<<192, 512, 0, stream>>>(Xb, WT_attn, b_attn, Qp, Kp, VT);
  attn_mfma<<<512, 512, 0, stream>>>(Qp, Kp, VT, Aattn);
  gemm_out<<<dim3(32, 8), 256, 0, stream>>>(Aattn, WT_proj, b_proj, out);
}